// Round 9
// baseline (275.720 us; speedup 1.0000x reference)
//
#include <hip/hip_runtime.h>

#define N_NODES 50000
#define N_EDGES 800000
#define D 128
#define N_LAYERS 3
#define OUT_F 16
#define N_GRAPHS 128
#define NBUCK 391            // ceil(50000/128) buckets of 128 nodes
#define EPB 4096             // edges per partition block
#define NB3 ((N_EDGES + EPB - 1) / EPB)  // 196
#define CAP 4096             // padded bucket capacity (mean 2048, sigma ~45)
#define NT32 ((N_NODES + 31) / 32)       // 1563 row-tiles of 32
#define PITCH 132            // LDS tile pitch in shorts (264B)
#define NCAST 6250           // cast blocks: 50000*128/4/256
#define NPREPW 96            // prep_w blocks: 24576/256

typedef __attribute__((ext_vector_type(8))) short short8;
typedef __attribute__((ext_vector_type(16))) float floatx16;

__device__ __forceinline__ unsigned short f2bf(float f) {
  unsigned int u = __float_as_uint(f);
  u += 0x7fff + ((u >> 16) & 1);   // RNE
  return (unsigned short)(u >> 16);
}
__device__ __forceinline__ float bf2f(unsigned short b) {
  return __uint_as_float(((unsigned int)b) << 16);
}
__device__ __forceinline__ float blo(unsigned v) { return __uint_as_float(v << 16); }
__device__ __forceinline__ float bhi(unsigned v) { return __uint_as_float(v & 0xffff0000u); }

// ====== prep_part: partition + cast x + weight frags in ONE dispatch ========
// (cursor is zeroed by hipMemsetAsync before this dispatch)
__global__ __launch_bounds__(256) void prep_part_kernel(
    const int* __restrict__ src, const int* __restrict__ dst,
    int* __restrict__ cursor, unsigned* __restrict__ pairs,
    const float* __restrict__ x, unsigned short* __restrict__ x16,
    const float* __restrict__ Wrel, const float* __restrict__ Wroot,
    unsigned short* __restrict__ wt) {
  __shared__ unsigned pk[EPB];
  __shared__ int hist[NBUCK];
  __shared__ int wcur[NBUCK];
  const int bid = blockIdx.x;
  const int t = threadIdx.x;
  if (bid < NB3) {                         // ---- edge partition ----
    const int e0 = bid * EPB;
    const int n = min(EPB, N_EDGES - e0);
    for (int i = t; i < NBUCK; i += 256) hist[i] = 0;
    __syncthreads();
    for (int i = t; i < n; i += 256) {
      int d = dst[e0 + i], s = src[e0 + i];
      pk[i] = ((unsigned)d << 16) | (unsigned)s;
      atomicAdd(&hist[d >> 7], 1);
    }
    __syncthreads();
    for (int i = t; i < NBUCK; i += 256)
      wcur[i] = i * CAP + (hist[i] ? atomicAdd(&cursor[i], hist[i]) : 0);
    __syncthreads();
    for (int i = t; i < n; i += 256) {
      unsigned p = pk[i];
      int pos = atomicAdd(&wcur[p >> 23], 1);
      pairs[pos] = p;
    }
  } else if (bid < NB3 + NCAST) {          // ---- cast x (4 floats/thread) ----
    const int i = (bid - NB3) * 256 + t;
    const float4 v = *(const float4*)&x[(size_t)i * 4];
    uint2 o;
    o.x = f2bf(v.x) | ((unsigned)f2bf(v.y) << 16);
    o.y = f2bf(v.z) | ((unsigned)f2bf(v.w) << 16);
    *(uint2*)&x16[(size_t)i * 4] = o;
  } else {                                 // ---- weight fragments ----
    const int idx = (bid - NB3 - NCAST) * 256 + t;
    const int lane = idx & 63;
    const int kst = (idx >> 6) & 31;
    const int nt = (idx >> 11) & 1;
    const int half = (idx >> 12) & 1;
    const int l = idx >> 13;
    const int n = half * 64 + nt * 32 + (lane & 31);
    const int kx0 = kst * 16 + (lane >> 5) * 8;
    const int seg = kx0 >> 7;              // same seg for all 8 j
    const int k0 = kx0 & 127;
    const int mat = seg >> 1, lo = seg & 1;
    const float* W = (mat ? Wroot : Wrel) + (size_t)l * D * D;
    unsigned short v[8];
#pragma unroll
    for (int j = 0; j < 8; ++j) {
      float w = W[(size_t)(k0 + j) * D + n];
      unsigned short hi = f2bf(w);
      v[j] = lo ? f2bf(w - bf2f(hi)) : hi;
    }
    unsigned short* dstp =
        wt + ((size_t)l * 128 + (half * 2 + nt) * 32 + kst) * 512 + lane * 8;
    *(uint4*)dstp = *(const uint4*)v;
  }
}

__global__ __launch_bounds__(256) void bucket_sort_kernel(
    const unsigned* __restrict__ pairs, const int* __restrict__ cursor,
    int* __restrict__ rowbeg, int* __restrict__ rowend, int* __restrict__ esrc) {
  __shared__ unsigned pk[CAP];
  __shared__ int sorted[CAP];
  __shared__ int hist[128], off[128], cur[128];
  const int bkt = blockIdx.x;
  const int t = threadIdx.x;
  const int beg = bkt * CAP;
  const int cnt = cursor[bkt];
  if (t < 128) hist[t] = 0;
  __syncthreads();
  for (int i = t; i < cnt; i += 256) {
    unsigned p = pairs[beg + i];
    pk[i] = p;
    atomicAdd(&hist[(p >> 16) & 127], 1);
  }
  __syncthreads();
  if (t < 128) off[t] = hist[t];
  __syncthreads();
  for (int o = 1; o < 128; o <<= 1) {
    int x = (t < 128 && t >= o) ? off[t - o] : 0;
    __syncthreads();
    if (t < 128) off[t] += x;
    __syncthreads();
  }
  if (t < 128) {
    int node = bkt * 128 + t;
    if (node < N_NODES) {
      rowbeg[node] = beg + off[t] - hist[t];
      rowend[node] = beg + off[t];
    }
    cur[t] = off[t] - hist[t];
  }
  __syncthreads();
  for (int i = t; i < cnt; i += 256) {
    unsigned p = pk[i];
    int pos = atomicAdd(&cur[(p >> 16) & 127], 1);
    sorted[pos] = (int)(p & 0xFFFFu);
  }
  __syncthreads();
  for (int i = t; i < cnt; i += 256) esrc[beg + i] = sorted[i];
}

// ========== FUSED layer v9: r4 structure + real VGPR budget =================
// __launch_bounds__(512, 4): r4's (512,8) forced 32 VGPRs -> the gather's
// in-flight uint4s couldn't be register-resident -> per-wave load ILP ~1 ->
// exposed LLC latency (2 TB/s). Now <=128 VGPRs + 8-edge unroll restores
// 8 independent 1KB row-loads in flight per 16-lane group.
// Gather: 32 groups x 16 lanes, one row/group. MFMA: waves 0-3 rel chain,
// 4-7 root chain; redB exchange; rel waves write bias+relu output.
__global__ __launch_bounds__(512, 4) void layer_kernel(
    const unsigned short* __restrict__ h,     // [N][128] bf16 row-major
    const int* __restrict__ rowbeg, const int* __restrict__ rowend,
    const int* __restrict__ esrc,
    const unsigned short* __restrict__ wt,    // this layer's 128KB frag block
    const float* __restrict__ brel,
    unsigned short* __restrict__ outp) {      // [N][128] bf16 row-major
  __shared__ unsigned short atile[32 * PITCH];  // agg tile   (8.4 KB)
  __shared__ unsigned short htile[32 * PITCH];  // root tile  (8.4 KB)
  __shared__ float redB[4][16][64];             // root-chain acc (16 KB)
  const int t = threadIdx.x;
  const int r0 = blockIdx.x * 32;
  const int g = t >> 4, li = t & 15;            // 32 groups x 16 lanes
  const int row = r0 + g;
  const unsigned short* hp = h + (size_t)li * 8;

  // ---- stage root row (independent; issue first) ----
  if (row < N_NODES) {
    *(uint4*)&htile[g * PITCH + li * 8] =
        *(const uint4*)&h[(size_t)row * D + li * 8];
  } else {
    const uint4 z = {0, 0, 0, 0};
    *(uint4*)&htile[g * PITCH + li * 8] = z;
  }

  // ---- gather: one row per 16-lane group; 8-edge unroll (8 KB in flight) --
  int beg = 0, end = 0;
  if (row < N_NODES) { beg = rowbeg[row]; end = rowend[row]; }
  float a0 = 0, a1 = 0, a2 = 0, a3 = 0, a4 = 0, a5 = 0, a6 = 0, a7 = 0;
  int e = beg;
  for (; e + 8 <= end; e += 8) {
    const int s0 = esrc[e],     s1 = esrc[e + 1];
    const int s2 = esrc[e + 2], s3 = esrc[e + 3];
    const int s4 = esrc[e + 4], s5 = esrc[e + 5];
    const int s6 = esrc[e + 6], s7 = esrc[e + 7];
    const uint4 v0 = *(const uint4*)&hp[(size_t)s0 * D];
    const uint4 v1 = *(const uint4*)&hp[(size_t)s1 * D];
    const uint4 v2 = *(const uint4*)&hp[(size_t)s2 * D];
    const uint4 v3 = *(const uint4*)&hp[(size_t)s3 * D];
    const uint4 v4 = *(const uint4*)&hp[(size_t)s4 * D];
    const uint4 v5 = *(const uint4*)&hp[(size_t)s5 * D];
    const uint4 v6 = *(const uint4*)&hp[(size_t)s6 * D];
    const uint4 v7 = *(const uint4*)&hp[(size_t)s7 * D];
    a0 += (blo(v0.x) + blo(v1.x) + blo(v2.x) + blo(v3.x)) +
          (blo(v4.x) + blo(v5.x) + blo(v6.x) + blo(v7.x));
    a1 += (bhi(v0.x) + bhi(v1.x) + bhi(v2.x) + bhi(v3.x)) +
          (bhi(v4.x) + bhi(v5.x) + bhi(v6.x) + bhi(v7.x));
    a2 += (blo(v0.y) + blo(v1.y) + blo(v2.y) + blo(v3.y)) +
          (blo(v4.y) + blo(v5.y) + blo(v6.y) + blo(v7.y));
    a3 += (bhi(v0.y) + bhi(v1.y) + bhi(v2.y) + bhi(v3.y)) +
          (bhi(v4.y) + bhi(v5.y) + bhi(v6.y) + bhi(v7.y));
    a4 += (blo(v0.z) + blo(v1.z) + blo(v2.z) + blo(v3.z)) +
          (blo(v4.z) + blo(v5.z) + blo(v6.z) + blo(v7.z));
    a5 += (bhi(v0.z) + bhi(v1.z) + bhi(v2.z) + bhi(v3.z)) +
          (bhi(v4.z) + bhi(v5.z) + bhi(v6.z) + bhi(v7.z));
    a6 += (blo(v0.w) + blo(v1.w) + blo(v2.w) + blo(v3.w)) +
          (blo(v4.w) + blo(v5.w) + blo(v6.w) + blo(v7.w));
    a7 += (bhi(v0.w) + bhi(v1.w) + bhi(v2.w) + bhi(v3.w)) +
          (bhi(v4.w) + bhi(v5.w) + bhi(v6.w) + bhi(v7.w));
  }
  for (; e + 4 <= end; e += 4) {
    const int s0 = esrc[e],     s1 = esrc[e + 1];
    const int s2 = esrc[e + 2], s3 = esrc[e + 3];
    const uint4 v0 = *(const uint4*)&hp[(size_t)s0 * D];
    const uint4 v1 = *(const uint4*)&hp[(size_t)s1 * D];
    const uint4 v2 = *(const uint4*)&hp[(size_t)s2 * D];
    const uint4 v3 = *(const uint4*)&hp[(size_t)s3 * D];
    a0 += blo(v0.x) + blo(v1.x) + blo(v2.x) + blo(v3.x);
    a1 += bhi(v0.x) + bhi(v1.x) + bhi(v2.x) + bhi(v3.x);
    a2 += blo(v0.y) + blo(v1.y) + blo(v2.y) + blo(v3.y);
    a3 += bhi(v0.y) + bhi(v1.y) + bhi(v2.y) + bhi(v3.y);
    a4 += blo(v0.z) + blo(v1.z) + blo(v2.z) + blo(v3.z);
    a5 += bhi(v0.z) + bhi(v1.z) + bhi(v2.z) + bhi(v3.z);
    a6 += blo(v0.w) + blo(v1.w) + blo(v2.w) + blo(v3.w);
    a7 += bhi(v0.w) + bhi(v1.w) + bhi(v2.w) + bhi(v3.w);
  }
  for (; e < end; ++e) {
    const uint4 v0 = *(const uint4*)&hp[(size_t)esrc[e] * D];
    a0 += blo(v0.x); a1 += bhi(v0.x);
    a2 += blo(v0.y); a3 += bhi(v0.y);
    a4 += blo(v0.z); a5 += bhi(v0.z);
    a6 += blo(v0.w); a7 += bhi(v0.w);
  }
  {
    uint4 o;
    o.x = f2bf(a0) | ((unsigned)f2bf(a1) << 16);
    o.y = f2bf(a2) | ((unsigned)f2bf(a3) << 16);
    o.z = f2bf(a4) | ((unsigned)f2bf(a5) << 16);
    o.w = f2bf(a6) | ((unsigned)f2bf(a7) << 16);
    *(uint4*)&atile[g * PITCH + li * 8] = o;
  }
  __syncthreads();

  // ---- MFMA: wave = (phase p, chain); 16 ksteps per wave ----
  const int wave = t >> 6, lane = t & 63;
  const int p = wave & 3, chain = wave >> 2;    // chain 0=rel(agg), 1=root(h)
  const int r2 = lane & 31, hseg = lane >> 5;
  const unsigned short* tile = chain ? htile : atile;
  short8 fr[8];
#pragma unroll
  for (int i = 0; i < 8; ++i)
    fr[i] = *(const short8*)&tile[r2 * PITCH + i * 16 + hseg * 8];
  const unsigned short* ws = wt + (size_t)(p * 32 + chain * 16) * 512;
  floatx16 acc = {0.f};
#pragma unroll
  for (int k = 0; k < 16; ++k) {
    const short8 b = *(const short8*)&ws[(size_t)k * 512 + lane * 8];
    acc = __builtin_amdgcn_mfma_f32_32x32x16_bf16(fr[k & 7], b, acc, 0, 0, 0);
  }
  if (chain) {
#pragma unroll
    for (int reg = 0; reg < 16; ++reg) redB[p][reg][lane] = acc[reg];
  }
  __syncthreads();
  if (!chain) {
    const int cb = p * 32 + r2;
    const float bias = brel[cb];
#pragma unroll
    for (int reg = 0; reg < 16; ++reg) {
      const int orow = r0 + (reg & 3) + 8 * (reg >> 2) + 4 * hseg;
      if (orow < N_NODES)
        outp[(size_t)orow * D + cb] =
            f2bf(fmaxf(acc[reg] + redB[p][reg][lane] + bias, 0.f));
    }
  }
}

// ============= pool (segment ranges; batch sorted) + MLP head ===============
__device__ __forceinline__ int lb_search(const int* __restrict__ a, int n, int key) {
  int lo = 0, hi = n;
  while (lo < hi) {
    int m = (lo + hi) >> 1;
    if (a[m] < key) lo = m + 1; else hi = m;
  }
  return lo;
}

__global__ __launch_bounds__(256) void pool_head_kernel(
    const unsigned short* __restrict__ h, const int* __restrict__ batch,
    const float* __restrict__ W1, const float* __restrict__ b1,
    const float* __restrict__ W2, const float* __restrict__ b2,
    float* __restrict__ out) {
  __shared__ float sums_lds[16][128];
  __shared__ float pooled[128];
  __shared__ float hidden[128];
  __shared__ int range[2];
  const int g = blockIdx.x;
  const int t = threadIdx.x;
  if (t < 2) range[t] = lb_search(batch, N_NODES, g + t);
  __syncthreads();
  const int lo = range[0], hi = range[1];
  const int rg = t >> 4, cg = t & 15;
  float a0 = 0, a1 = 0, a2 = 0, a3 = 0, a4 = 0, a5 = 0, a6 = 0, a7 = 0;
  for (int n = lo + rg; n < hi; n += 16) {
    const uint4 v = *(const uint4*)&h[(size_t)n * D + cg * 8];
    a0 += blo(v.x); a1 += bhi(v.x);
    a2 += blo(v.y); a3 += bhi(v.y);
    a4 += blo(v.z); a5 += bhi(v.z);
    a6 += blo(v.w); a7 += bhi(v.w);
  }
  sums_lds[rg][cg * 8 + 0] = a0; sums_lds[rg][cg * 8 + 1] = a1;
  sums_lds[rg][cg * 8 + 2] = a2; sums_lds[rg][cg * 8 + 3] = a3;
  sums_lds[rg][cg * 8 + 4] = a4; sums_lds[rg][cg * 8 + 5] = a5;
  sums_lds[rg][cg * 8 + 6] = a6; sums_lds[rg][cg * 8 + 7] = a7;
  __syncthreads();
  if (t < 128) {
    float s = 0.f;
#pragma unroll
    for (int r = 0; r < 16; ++r) s += sums_lds[r][t];
    pooled[t] = s / fmaxf((float)(hi - lo), 1.f);
  }
  __syncthreads();
  if (t < 128) {
    float a = b1[t];
    for (int k = 0; k < D; ++k) a += pooled[k] * W1[k * D + t];
    hidden[t] = a;
  }
  __syncthreads();
  if (t < OUT_F) {
    float o = b2[t];
    for (int k = 0; k < D; ++k) o += hidden[k] * W2[k * OUT_F + t];
    out[(size_t)g * OUT_F + t] = o;
  }
}

// ============================== launch ======================================
extern "C" void kernel_launch(void* const* d_in, const int* in_sizes, int n_in,
                              void* d_out, int out_size, void* d_ws, size_t ws_size,
                              hipStream_t stream) {
  const float* x     = (const float*)d_in[0];
  const int*   ei    = (const int*)d_in[1];
  const int*   batch = (const int*)d_in[2];
  const float* Wrel  = (const float*)d_in[3];
  const float* brel  = (const float*)d_in[4];
  const float* Wroot = (const float*)d_in[5];
  const float* W1    = (const float*)d_in[6];
  const float* b1    = (const float*)d_in[7];
  const float* W2    = (const float*)d_in[8];
  const float* b2    = (const float*)d_in[9];
  float* out = (float*)d_out;

  const size_t ND = (size_t)N_NODES * D;
  unsigned short* bufA = (unsigned short*)d_ws;            // N*D bf16
  unsigned short* bufB = bufA + ND;                        // N*D bf16
  unsigned short* bufC = bufB + ND;                        // N*D bf16 (x16)
  unsigned short* wt   = bufC + ND;                        // 3*128*512 bf16
  int* rowbeg = (int*)(wt + (size_t)N_LAYERS * 128 * 512); // N
  int* rowend = rowbeg + N_NODES;                          // N
  int* esrc   = rowend + N_NODES;                          // NBUCK*CAP
  unsigned* pairs = (unsigned*)(esrc + (size_t)NBUCK * CAP);  // NBUCK*CAP
  int* cursor = (int*)(pairs + (size_t)NBUCK * CAP);       // NBUCK

  const int* esrc_in = ei;
  const int* edst_in = ei + N_EDGES;

  // ---- prep (partition + cast + weight frags) then bucket sort ----
  hipMemsetAsync(cursor, 0, NBUCK * sizeof(int), stream);
  prep_part_kernel<<<NB3 + NCAST + NPREPW, 256, 0, stream>>>(
      esrc_in, edst_in, cursor, pairs, x, bufC, Wrel, Wroot, wt);
  bucket_sort_kernel<<<NBUCK, 256, 0, stream>>>(pairs, cursor, rowbeg, rowend, esrc);

  // ---- 3 fused layers ----
  const size_t WL = (size_t)128 * 512;
  layer_kernel<<<NT32, 512, 0, stream>>>(bufC, rowbeg, rowend, esrc,
                                         wt, brel, bufA);
  layer_kernel<<<NT32, 512, 0, stream>>>(bufA, rowbeg, rowend, esrc,
                                         wt + WL, brel + D, bufB);
  layer_kernel<<<NT32, 512, 0, stream>>>(bufB, rowbeg, rowend, esrc,
                                         wt + 2 * WL, brel + 2 * D, bufA);

  pool_head_kernel<<<N_GRAPHS, 256, 0, stream>>>(bufA, batch, W1, b1, W2, b2, out);
}

// Round 11
// 268.743 us; speedup vs baseline: 1.0260x; 1.0260x over previous
//
#include <hip/hip_runtime.h>

#define N_NODES 50000
#define N_EDGES 800000
#define D 128
#define N_LAYERS 3
#define OUT_F 16
#define N_GRAPHS 128
#define NBUCK 391            // ceil(50000/128) buckets of 128 nodes
#define EPB 4096             // edges per partition block
#define NB3 ((N_EDGES + EPB - 1) / EPB)  // 196
#define CAP 4096             // padded bucket capacity (mean 2048, sigma ~45)
#define NT32 ((N_NODES + 31) / 32)       // 1563 row-tiles of 32
#define NUNIT 196            // units of 256 nodes (= gemm blocks)
#define NAGGC 400            // agg blocks per XCD class (400*16 = 6400 = 25 units)
#define NCAST 6250           // cast blocks: 50000*128/4/256
#define NPREPW 96            // prep_w blocks: 24576/256

typedef __attribute__((ext_vector_type(8))) short short8;
typedef __attribute__((ext_vector_type(16))) float floatx16;

__device__ __forceinline__ unsigned short f2bf(float f) {
  unsigned int u = __float_as_uint(f);
  u += 0x7fff + ((u >> 16) & 1);   // RNE
  return (unsigned short)(u >> 16);
}
__device__ __forceinline__ float bf2f(unsigned short b) {
  return __uint_as_float(((unsigned int)b) << 16);
}
__device__ __forceinline__ float blo(unsigned v) { return __uint_as_float(v << 16); }
__device__ __forceinline__ float bhi(unsigned v) { return __uint_as_float(v & 0xffff0000u); }

// ====== prep_part: partition + cast x + weight frags in ONE dispatch ========
__global__ __launch_bounds__(256) void prep_part_kernel(
    const int* __restrict__ src, const int* __restrict__ dst,
    int* __restrict__ cursor, unsigned* __restrict__ pairs,
    const float* __restrict__ x, unsigned short* __restrict__ x16,
    const float* __restrict__ Wrel, const float* __restrict__ Wroot,
    unsigned short* __restrict__ wt) {
  __shared__ unsigned pk[EPB];
  __shared__ int hist[NBUCK];
  __shared__ int wcur[NBUCK];
  const int bid = blockIdx.x;
  const int t = threadIdx.x;
  if (bid < NB3) {                         // ---- edge partition ----
    const int e0 = bid * EPB;
    const int n = min(EPB, N_EDGES - e0);
    for (int i = t; i < NBUCK; i += 256) hist[i] = 0;
    __syncthreads();
    for (int i = t; i < n; i += 256) {
      int d = dst[e0 + i], s = src[e0 + i];
      pk[i] = ((unsigned)d << 16) | (unsigned)s;
      atomicAdd(&hist[d >> 7], 1);
    }
    __syncthreads();
    for (int i = t; i < NBUCK; i += 256)
      wcur[i] = i * CAP + (hist[i] ? atomicAdd(&cursor[i], hist[i]) : 0);
    __syncthreads();
    for (int i = t; i < n; i += 256) {
      unsigned p = pk[i];
      int pos = atomicAdd(&wcur[p >> 23], 1);
      pairs[pos] = p;
    }
  } else if (bid < NB3 + NCAST) {          // ---- cast x (4 floats/thread) ----
    const int i = (bid - NB3) * 256 + t;
    const float4 v = *(const float4*)&x[(size_t)i * 4];
    uint2 o;
    o.x = f2bf(v.x) | ((unsigned)f2bf(v.y) << 16);
    o.y = f2bf(v.z) | ((unsigned)f2bf(v.w) << 16);
    *(uint2*)&x16[(size_t)i * 4] = o;
  } else {                                 // ---- weight fragments ----
    const int idx = (bid - NB3 - NCAST) * 256 + t;
    const int lane = idx & 63;
    const int kst = (idx >> 6) & 31;
    const int nt = (idx >> 11) & 1;
    const int half = (idx >> 12) & 1;
    const int l = idx >> 13;
    const int n = half * 64 + nt * 32 + (lane & 31);
    const int kx0 = kst * 16 + (lane >> 5) * 8;
    const int seg = kx0 >> 7;              // same seg for all 8 j
    const int k0 = kx0 & 127;
    const int mat = seg >> 1, lo = seg & 1;
    const float* W = (mat ? Wroot : Wrel) + (size_t)l * D * D;
    unsigned short v[8];
#pragma unroll
    for (int j = 0; j < 8; ++j) {
      float w = W[(size_t)(k0 + j) * D + n];
      unsigned short hi = f2bf(w);
      v[j] = lo ? f2bf(w - bf2f(hi)) : hi;
    }
    unsigned short* dstp =
        wt + ((size_t)l * 128 + (half * 2 + nt) * 32 + kst) * 512 + lane * 8;
    *(uint4*)dstp = *(const uint4*)v;
  }
}

__global__ __launch_bounds__(256) void bucket_sort_kernel(
    const unsigned* __restrict__ pairs, const int* __restrict__ cursor,
    int* __restrict__ rowbeg, int* __restrict__ rowend, int* __restrict__ esrc) {
  __shared__ unsigned pk[CAP];
  __shared__ int sorted[CAP];
  __shared__ int hist[128], off[128], cur[128];
  const int bkt = blockIdx.x;
  const int t = threadIdx.x;
  const int beg = bkt * CAP;
  const int cnt = cursor[bkt];
  if (t < 128) hist[t] = 0;
  __syncthreads();
  for (int i = t; i < cnt; i += 256) {
    unsigned p = pairs[beg + i];
    pk[i] = p;
    atomicAdd(&hist[(p >> 16) & 127], 1);
  }
  __syncthreads();
  if (t < 128) off[t] = hist[t];
  __syncthreads();
  for (int o = 1; o < 128; o <<= 1) {
    int x = (t < 128 && t >= o) ? off[t - o] : 0;
    __syncthreads();
    if (t < 128) off[t] += x;
    __syncthreads();
  }
  if (t < 128) {
    int node = bkt * 128 + t;
    if (node < N_NODES) {
      rowbeg[node] = beg + off[t] - hist[t];
      rowend[node] = beg + off[t];
    }
    cur[t] = off[t] - hist[t];
  }
  __syncthreads();
  for (int i = t; i < cnt; i += 256) {
    unsigned p = pk[i];
    int pos = atomicAdd(&cur[(p >> 16) & 127], 1);
    sorted[pos] = (int)(p & 0xFFFFu);
  }
  __syncthreads();
  for (int i = t; i < cnt; i += 256) esrc[beg + i] = sorted[i];
}

// ===== aggregate: XCD-affine node permutation ==============================
// Convention: unit u = nodes [u*256, u*256+256) lives on XCD u%8 (round-robin
// bid%8 dispatch). Agg block a: class x=a&7, slot s=a>>3; class-local index
// c = s*16+g -> unit u = x+8*(c>>8), node n = u*256+(c&255). Each class
// covers 25 units (u = x..x+192 step 8) = 6400 c-values -> NAGGC=400 blocks
// (r10 bug: 392 left 384 nodes uncovered). Writes land in XCD u%8's
// write-back L2, where the SAME XCD's gemm block (b=u) re-reads them.
// Gather inner loop = round-0 geometry (16 lanes/node, 4-edge unroll).
__global__ __launch_bounds__(256) void agg_kernel(
    const unsigned short* __restrict__ h,
    const int* __restrict__ rowbeg, const int* __restrict__ rowend,
    const int* __restrict__ esrc, unsigned short* __restrict__ agg) {
  const int bid = blockIdx.x;              // 8 * 400 = 3200
  const int x = bid & 7, s = bid >> 3;
  const int t = threadIdx.x;
  const int c = s * 16 + (t >> 4);         // class-local node index [0,6400)
  const int u = x + 8 * (c >> 8);          // unit (may exceed 195 on tail)
  const int n = u * 256 + (c & 255);
  const int lane = t & 15;
  if (n >= N_NODES) return;
  const int beg = rowbeg[n], end = rowend[n];
  float a0 = 0, a1 = 0, a2 = 0, a3 = 0, a4 = 0, a5 = 0, a6 = 0, a7 = 0;
  int e = beg;
  for (; e + 4 <= end; e += 4) {
    const int s0 = esrc[e],     s1 = esrc[e + 1];
    const int s2 = esrc[e + 2], s3 = esrc[e + 3];
    const uint4 v0 = *(const uint4*)&h[(size_t)s0 * D + lane * 8];
    const uint4 v1 = *(const uint4*)&h[(size_t)s1 * D + lane * 8];
    const uint4 v2 = *(const uint4*)&h[(size_t)s2 * D + lane * 8];
    const uint4 v3 = *(const uint4*)&h[(size_t)s3 * D + lane * 8];
    a0 += blo(v0.x) + blo(v1.x) + blo(v2.x) + blo(v3.x);
    a1 += bhi(v0.x) + bhi(v1.x) + bhi(v2.x) + bhi(v3.x);
    a2 += blo(v0.y) + blo(v1.y) + blo(v2.y) + blo(v3.y);
    a3 += bhi(v0.y) + bhi(v1.y) + bhi(v2.y) + bhi(v3.y);
    a4 += blo(v0.z) + blo(v1.z) + blo(v2.z) + blo(v3.z);
    a5 += bhi(v0.z) + bhi(v1.z) + bhi(v2.z) + bhi(v3.z);
    a6 += blo(v0.w) + blo(v1.w) + blo(v2.w) + blo(v3.w);
    a7 += bhi(v0.w) + bhi(v1.w) + bhi(v2.w) + bhi(v3.w);
  }
  for (; e < end; ++e) {
    const int s0 = esrc[e];
    const uint4 v0 = *(const uint4*)&h[(size_t)s0 * D + lane * 8];
    a0 += blo(v0.x); a1 += bhi(v0.x);
    a2 += blo(v0.y); a3 += bhi(v0.y);
    a4 += blo(v0.z); a5 += bhi(v0.z);
    a6 += blo(v0.w); a7 += bhi(v0.w);
  }
  uint4 o;
  o.x = f2bf(a0) | ((unsigned)f2bf(a1) << 16);
  o.y = f2bf(a2) | ((unsigned)f2bf(a3) << 16);
  o.z = f2bf(a4) | ((unsigned)f2bf(a5) << 16);
  o.w = f2bf(a6) | ((unsigned)f2bf(a7) << 16);
  *(uint4*)&agg[(size_t)n * D + lane * 8] = o;
}

// ========== GEMM v10: block = unit (256 rows), XCD-affine ===================
// 196 blocks x 512 thr; wave w = tile bid*8+w -> block b reads exactly the
// rows unit b's agg blocks wrote on the SAME XCD (b%8) -> A and root reads
// are L2 hits. B staged once per block in two 64KB LDS halves -> 25 MB B
// traffic. Output rows written back to the same XCD's L2 for the next
// layer's gemm. Epilogue/math order identical to r8 (absmax-stable).
__global__ __launch_bounds__(512, 2) void gemm_kernel(
    const unsigned short* __restrict__ agg, const unsigned short* __restrict__ hv,
    const unsigned short* __restrict__ wt,  // this layer's 128KB frag block
    const float* __restrict__ brel,
    unsigned short* __restrict__ outp) {
  __shared__ unsigned short blds[32768];        // 64 KB: current B half
  const int t = threadIdx.x;
  const int wave = t >> 6, lane = t & 63;
  const int r2 = lane & 31, hseg = lane >> 5;
  const int tile = blockIdx.x * 8 + wave;
  const int r0 = tile * 32;
  int arow = r0 + r2;
  if (arow >= N_NODES) arow = N_NODES - 1;

  // ---- A/h fragments straight to registers (L2-local now) ----
  short8 ag[8], hh[8];
  const unsigned short* ap = agg + (size_t)arow * D + hseg * 8;
  const unsigned short* hp = hv + (size_t)arow * D + hseg * 8;
#pragma unroll
  for (int i = 0; i < 8; ++i) {
    ag[i] = *(const short8*)(ap + i * 16);
    hh[i] = *(const short8*)(hp + i * 16);
  }

  // ---- 2 B-halves x 2 phases ----
#pragma unroll
  for (int pp = 0; pp < 2; ++pp) {
    if (pp) __syncthreads();                    // prev-half reads done
    const unsigned short* ws = wt + (size_t)pp * 32768;
#pragma unroll
    for (int j = 0; j < 8; ++j) {
      const int idx = t + j * 512;              // 4096 uint4 units = 64KB
      *(uint4*)&blds[idx * 8] = *(const uint4*)&ws[idx * 8];
    }
    __syncthreads();
#pragma unroll
    for (int p2 = 0; p2 < 2; ++p2) {
      floatx16 acc = {0.f};
#pragma unroll
      for (int kst = 0; kst < 32; ++kst) {
        const short8 af = (kst < 16) ? ag[kst & 7] : hh[kst & 7];
        const short8 b = *(const short8*)&blds[(p2 * 32 + kst) * 512 + lane * 8];
        acc = __builtin_amdgcn_mfma_f32_32x32x16_bf16(af, b, acc, 0, 0, 0);
      }
      const int cb = (pp * 2 + p2) * 32 + r2;
      const float bias = brel[cb];
#pragma unroll
      for (int reg = 0; reg < 16; ++reg) {
        const int orow = r0 + (reg & 3) + 8 * (reg >> 2) + 4 * hseg;
        if (orow < N_NODES)
          outp[(size_t)orow * D + cb] = f2bf(fmaxf(acc[reg] + bias, 0.f));
      }
    }
  }
}

// ============= pool (segment ranges; batch sorted) + MLP head ===============
__device__ __forceinline__ int lb_search(const int* __restrict__ a, int n, int key) {
  int lo = 0, hi = n;
  while (lo < hi) {
    int m = (lo + hi) >> 1;
    if (a[m] < key) lo = m + 1; else hi = m;
  }
  return lo;
}

__global__ __launch_bounds__(256) void pool_head_kernel(
    const unsigned short* __restrict__ h, const int* __restrict__ batch,
    const float* __restrict__ W1, const float* __restrict__ b1,
    const float* __restrict__ W2, const float* __restrict__ b2,
    float* __restrict__ out) {
  __shared__ float sums_lds[16][128];
  __shared__ float pooled[128];
  __shared__ float hidden[128];
  __shared__ int range[2];
  const int g = blockIdx.x;
  const int t = threadIdx.x;
  if (t < 2) range[t] = lb_search(batch, N_NODES, g + t);
  __syncthreads();
  const int lo = range[0], hi = range[1];
  const int rg = t >> 4, cg = t & 15;
  float a0 = 0, a1 = 0, a2 = 0, a3 = 0, a4 = 0, a5 = 0, a6 = 0, a7 = 0;
  for (int n = lo + rg; n < hi; n += 16) {
    const uint4 v = *(const uint4*)&h[(size_t)n * D + cg * 8];
    a0 += blo(v.x); a1 += bhi(v.x);
    a2 += blo(v.y); a3 += bhi(v.y);
    a4 += blo(v.z); a5 += bhi(v.z);
    a6 += blo(v.w); a7 += bhi(v.w);
  }
  sums_lds[rg][cg * 8 + 0] = a0; sums_lds[rg][cg * 8 + 1] = a1;
  sums_lds[rg][cg * 8 + 2] = a2; sums_lds[rg][cg * 8 + 3] = a3;
  sums_lds[rg][cg * 8 + 4] = a4; sums_lds[rg][cg * 8 + 5] = a5;
  sums_lds[rg][cg * 8 + 6] = a6; sums_lds[rg][cg * 8 + 7] = a7;
  __syncthreads();
  if (t < 128) {
    float s = 0.f;
#pragma unroll
    for (int r = 0; r < 16; ++r) s += sums_lds[r][t];
    pooled[t] = s / fmaxf((float)(hi - lo), 1.f);
  }
  __syncthreads();
  if (t < 128) {
    float a = b1[t];
    for (int k = 0; k < D; ++k) a += pooled[k] * W1[k * D + t];
    hidden[t] = a;
  }
  __syncthreads();
  if (t < OUT_F) {
    float o = b2[t];
    for (int k = 0; k < D; ++k) o += hidden[k] * W2[k * OUT_F + t];
    out[(size_t)g * OUT_F + t] = o;
  }
}

// ============================== launch ======================================
extern "C" void kernel_launch(void* const* d_in, const int* in_sizes, int n_in,
                              void* d_out, int out_size, void* d_ws, size_t ws_size,
                              hipStream_t stream) {
  const float* x     = (const float*)d_in[0];
  const int*   ei    = (const int*)d_in[1];
  const int*   batch = (const int*)d_in[2];
  const float* Wrel  = (const float*)d_in[3];
  const float* brel  = (const float*)d_in[4];
  const float* Wroot = (const float*)d_in[5];
  const float* W1    = (const float*)d_in[6];
  const float* b1    = (const float*)d_in[7];
  const float* W2    = (const float*)d_in[8];
  const float* b2    = (const float*)d_in[9];
  float* out = (float*)d_out;

  const size_t ND = (size_t)N_NODES * D;
  unsigned short* bufA = (unsigned short*)d_ws;            // N*D bf16
  unsigned short* bufB = bufA + ND;                        // N*D bf16 (agg)
  unsigned short* bufC = bufB + ND;                        // N*D bf16 (x16)
  unsigned short* wt   = bufC + ND;                        // 3*128*512 bf16
  int* rowbeg = (int*)(wt + (size_t)N_LAYERS * 128 * 512); // N
  int* rowend = rowbeg + N_NODES;                          // N
  int* esrc   = rowend + N_NODES;                          // NBUCK*CAP
  unsigned* pairs = (unsigned*)(esrc + (size_t)NBUCK * CAP);  // NBUCK*CAP
  int* cursor = (int*)(pairs + (size_t)NBUCK * CAP);       // NBUCK

  const int* esrc_in = ei;
  const int* edst_in = ei + N_EDGES;

  // ---- prep (partition + cast + weight frags) then bucket sort ----
  hipMemsetAsync(cursor, 0, NBUCK * sizeof(int), stream);
  prep_part_kernel<<<NB3 + NCAST + NPREPW, 256, 0, stream>>>(
      esrc_in, edst_in, cursor, pairs, x, bufC, Wrel, Wroot, wt);
  bucket_sort_kernel<<<NBUCK, 256, 0, stream>>>(pairs, cursor, rowbeg, rowend, esrc);

  // ---- 3 layers: XCD-affine agg + XCD-affine unit GEMM ----
  const size_t WL = (size_t)128 * 512;
  const int agg_blocks = 8 * NAGGC;   // 3200
  // l0
  agg_kernel<<<agg_blocks, 256, 0, stream>>>(bufC, rowbeg, rowend, esrc, bufB);
  gemm_kernel<<<NUNIT, 512, 0, stream>>>(bufB, bufC, wt, brel, bufA);
  // l1
  agg_kernel<<<agg_blocks, 256, 0, stream>>>(bufA, rowbeg, rowend, esrc, bufB);
  gemm_kernel<<<NUNIT, 512, 0, stream>>>(bufB, bufA, wt + WL, brel + D, bufC);
  // l2
  agg_kernel<<<agg_blocks, 256, 0, stream>>>(bufC, rowbeg, rowend, esrc, bufB);
  gemm_kernel<<<NUNIT, 512, 0, stream>>>(bufB, bufC, wt + 2 * WL, brel + 2 * D, bufA);

  pool_head_kernel<<<N_GRAPHS, 256, 0, stream>>>(bufA, batch, W1, b1, W2, b2, out);
}

// Round 12
// 261.174 us; speedup vs baseline: 1.0557x; 1.0290x over previous
//
#include <hip/hip_runtime.h>

#define N_NODES 50000
#define N_EDGES 800000
#define D 128
#define N_LAYERS 3
#define OUT_F 16
#define N_GRAPHS 128
#define NBUCK 391            // ceil(50000/128) buckets of 128 nodes
#define EPB 4096             // edges per partition block
#define NB3 ((N_EDGES + EPB - 1) / EPB)  // 196
#define CAP 4096             // padded bucket capacity (mean 2048, sigma ~45)
#define NT32 ((N_NODES + 31) / 32)       // 1563 row-tiles of 32
#define PITCH 132            // LDS tile pitch in shorts (264B)
#define NCAST 6250           // cast blocks: 50000*128/4/256
#define NPREPW 96            // prep_w blocks: 24576/256

typedef __attribute__((ext_vector_type(8))) short short8;
typedef __attribute__((ext_vector_type(16))) float floatx16;

__device__ __forceinline__ unsigned short f2bf(float f) {
  unsigned int u = __float_as_uint(f);
  u += 0x7fff + ((u >> 16) & 1);   // RNE
  return (unsigned short)(u >> 16);
}
__device__ __forceinline__ float bf2f(unsigned short b) {
  return __uint_as_float(((unsigned int)b) << 16);
}
__device__ __forceinline__ float blo(unsigned v) { return __uint_as_float(v << 16); }
__device__ __forceinline__ float bhi(unsigned v) { return __uint_as_float(v & 0xffff0000u); }

// ====== prep_part: partition + cast x + weight frags in ONE dispatch ========
// (cursor zeroed by hipMemsetAsync before this dispatch)
__global__ __launch_bounds__(256) void prep_part_kernel(
    const int* __restrict__ src, const int* __restrict__ dst,
    int* __restrict__ cursor, unsigned* __restrict__ pairs,
    const float* __restrict__ x, unsigned short* __restrict__ x16,
    const float* __restrict__ Wrel, const float* __restrict__ Wroot,
    unsigned short* __restrict__ wt) {
  __shared__ unsigned pk[EPB];
  __shared__ int hist[NBUCK];
  __shared__ int wcur[NBUCK];
  const int bid = blockIdx.x;
  const int t = threadIdx.x;
  if (bid < NB3) {                         // ---- edge partition ----
    const int e0 = bid * EPB;
    const int n = min(EPB, N_EDGES - e0);
    for (int i = t; i < NBUCK; i += 256) hist[i] = 0;
    __syncthreads();
    for (int i = t; i < n; i += 256) {
      int d = dst[e0 + i], s = src[e0 + i];
      pk[i] = ((unsigned)d << 16) | (unsigned)s;
      atomicAdd(&hist[d >> 7], 1);
    }
    __syncthreads();
    for (int i = t; i < NBUCK; i += 256)
      wcur[i] = i * CAP + (hist[i] ? atomicAdd(&cursor[i], hist[i]) : 0);
    __syncthreads();
    for (int i = t; i < n; i += 256) {
      unsigned p = pk[i];
      int pos = atomicAdd(&wcur[p >> 23], 1);
      pairs[pos] = p;
    }
  } else if (bid < NB3 + NCAST) {          // ---- cast x (4 floats/thread) ----
    const int i = (bid - NB3) * 256 + t;
    const float4 v = *(const float4*)&x[(size_t)i * 4];
    uint2 o;
    o.x = f2bf(v.x) | ((unsigned)f2bf(v.y) << 16);
    o.y = f2bf(v.z) | ((unsigned)f2bf(v.w) << 16);
    *(uint2*)&x16[(size_t)i * 4] = o;
  } else {                                 // ---- weight fragments ----
    const int idx = (bid - NB3 - NCAST) * 256 + t;
    const int lane = idx & 63;
    const int kst = (idx >> 6) & 31;
    const int nt = (idx >> 11) & 1;
    const int half = (idx >> 12) & 1;
    const int l = idx >> 13;
    const int n = half * 64 + nt * 32 + (lane & 31);
    const int kx0 = kst * 16 + (lane >> 5) * 8;
    const int seg = kx0 >> 7;              // same seg for all 8 j
    const int k0 = kx0 & 127;
    const int mat = seg >> 1, lo = seg & 1;
    const float* W = (mat ? Wroot : Wrel) + (size_t)l * D * D;
    unsigned short v[8];
#pragma unroll
    for (int j = 0; j < 8; ++j) {
      float w = W[(size_t)(k0 + j) * D + n];
      unsigned short hi = f2bf(w);
      v[j] = lo ? f2bf(w - bf2f(hi)) : hi;
    }
    unsigned short* dstp =
        wt + ((size_t)l * 128 + (half * 2 + nt) * 32 + kst) * 512 + lane * 8;
    *(uint4*)dstp = *(const uint4*)v;
  }
}

__global__ __launch_bounds__(256) void bucket_sort_kernel(
    const unsigned* __restrict__ pairs, const int* __restrict__ cursor,
    int* __restrict__ rowbeg, int* __restrict__ rowend, int* __restrict__ esrc) {
  __shared__ unsigned pk[CAP];
  __shared__ int sorted[CAP];
  __shared__ int hist[128], off[128], cur[128];
  const int bkt = blockIdx.x;
  const int t = threadIdx.x;
  const int beg = bkt * CAP;
  const int cnt = cursor[bkt];
  if (t < 128) hist[t] = 0;
  __syncthreads();
  for (int i = t; i < cnt; i += 256) {
    unsigned p = pairs[beg + i];
    pk[i] = p;
    atomicAdd(&hist[(p >> 16) & 127], 1);
  }
  __syncthreads();
  if (t < 128) off[t] = hist[t];
  __syncthreads();
  for (int o = 1; o < 128; o <<= 1) {
    int x = (t < 128 && t >= o) ? off[t - o] : 0;
    __syncthreads();
    if (t < 128) off[t] += x;
    __syncthreads();
  }
  if (t < 128) {
    int node = bkt * 128 + t;
    if (node < N_NODES) {
      rowbeg[node] = beg + off[t] - hist[t];
      rowend[node] = beg + off[t];
    }
    cur[t] = off[t] - hist[t];
  }
  __syncthreads();
  for (int i = t; i < cnt; i += 256) {
    unsigned p = pk[i];
    int pos = atomicAdd(&cur[(p >> 16) & 127], 1);
    sorted[pos] = (int)(p & 0xFFFFu);
  }
  __syncthreads();
  for (int i = t; i < cnt; i += 256) esrc[beg + i] = sorted[i];
}

// ========== FUSED layer (r4 exact — best measured per-layer config) =========
// 8-wave block = 1 tile (32 rows). Gather: 32 groups x 16 lanes, one row per
// group, 4-edge unroll. (512,8) -> 32 VGPR: measured FASTER than (512,4)/44
// VGPR (47.8 vs 53.3 us) — more waves beats more ILP for this latency-bound
// gather. MFMA: waves 0-3 rel chain (agg x Wrel), 4-7 root chain (h x Wroot);
// root acc via redB LDS exchange; rel waves write bias+relu output.
__global__ __launch_bounds__(512, 8) void layer_kernel(
    const unsigned short* __restrict__ h,     // [N][128] bf16 row-major
    const int* __restrict__ rowbeg, const int* __restrict__ rowend,
    const int* __restrict__ esrc,
    const unsigned short* __restrict__ wt,    // this layer's 128KB frag block
    const float* __restrict__ brel,
    unsigned short* __restrict__ outp) {      // [N][128] bf16 row-major
  __shared__ unsigned short atile[32 * PITCH];  // agg tile   (8.4 KB)
  __shared__ unsigned short htile[32 * PITCH];  // root tile  (8.4 KB)
  __shared__ float redB[4][16][64];             // root-chain acc (16 KB)
  const int t = threadIdx.x;
  const int r0 = blockIdx.x * 32;
  const int g = t >> 4, li = t & 15;            // 32 groups x 16 lanes
  const int row = r0 + g;
  const unsigned short* hp = h + (size_t)li * 8;

  // ---- stage root row (coalesced; zero tail rows) ----
  if (row < N_NODES) {
    *(uint4*)&htile[g * PITCH + li * 8] =
        *(const uint4*)&h[(size_t)row * D + li * 8];
  } else {
    const uint4 z = {0, 0, 0, 0};
    *(uint4*)&htile[g * PITCH + li * 8] = z;
  }

  // ---- gather: one row per 16-lane group, 256B/edge coalesced ----
  int beg = 0, end = 0;
  if (row < N_NODES) { beg = rowbeg[row]; end = rowend[row]; }
  float a0 = 0, a1 = 0, a2 = 0, a3 = 0, a4 = 0, a5 = 0, a6 = 0, a7 = 0;
  int e = beg;
  for (; e + 4 <= end; e += 4) {
    const int s0 = esrc[e],     s1 = esrc[e + 1];
    const int s2 = esrc[e + 2], s3 = esrc[e + 3];
    const uint4 v0 = *(const uint4*)&hp[(size_t)s0 * D];
    const uint4 v1 = *(const uint4*)&hp[(size_t)s1 * D];
    const uint4 v2 = *(const uint4*)&hp[(size_t)s2 * D];
    const uint4 v3 = *(const uint4*)&hp[(size_t)s3 * D];
    a0 += blo(v0.x) + blo(v1.x) + blo(v2.x) + blo(v3.x);
    a1 += bhi(v0.x) + bhi(v1.x) + bhi(v2.x) + bhi(v3.x);
    a2 += blo(v0.y) + blo(v1.y) + blo(v2.y) + blo(v3.y);
    a3 += bhi(v0.y) + bhi(v1.y) + bhi(v2.y) + bhi(v3.y);
    a4 += blo(v0.z) + blo(v1.z) + blo(v2.z) + blo(v3.z);
    a5 += bhi(v0.z) + bhi(v1.z) + bhi(v2.z) + bhi(v3.z);
    a6 += blo(v0.w) + blo(v1.w) + blo(v2.w) + blo(v3.w);
    a7 += bhi(v0.w) + bhi(v1.w) + bhi(v2.w) + bhi(v3.w);
  }
  for (; e < end; ++e) {
    const uint4 v0 = *(const uint4*)&hp[(size_t)esrc[e] * D];
    a0 += blo(v0.x); a1 += bhi(v0.x);
    a2 += blo(v0.y); a3 += bhi(v0.y);
    a4 += blo(v0.z); a5 += bhi(v0.z);
    a6 += blo(v0.w); a7 += bhi(v0.w);
  }
  {
    uint4 o;
    o.x = f2bf(a0) | ((unsigned)f2bf(a1) << 16);
    o.y = f2bf(a2) | ((unsigned)f2bf(a3) << 16);
    o.z = f2bf(a4) | ((unsigned)f2bf(a5) << 16);
    o.w = f2bf(a6) | ((unsigned)f2bf(a7) << 16);
    *(uint4*)&atile[g * PITCH + li * 8] = o;
  }
  __syncthreads();

  // ---- MFMA: wave = (phase p, chain); 16 ksteps per wave ----
  const int wave = t >> 6, lane = t & 63;
  const int p = wave & 3, chain = wave >> 2;    // chain 0=rel(agg), 1=root(h)
  const int r2 = lane & 31, hseg = lane >> 5;
  const unsigned short* tile = chain ? htile : atile;
  short8 fr[8];
#pragma unroll
  for (int i = 0; i < 8; ++i)
    fr[i] = *(const short8*)&tile[r2 * PITCH + i * 16 + hseg * 8];
  const unsigned short* ws = wt + (size_t)(p * 32 + chain * 16) * 512;
  floatx16 acc = {0.f};
#pragma unroll
  for (int k = 0; k < 16; ++k) {
    const short8 b = *(const short8*)&ws[(size_t)k * 512 + lane * 8];
    acc = __builtin_amdgcn_mfma_f32_32x32x16_bf16(fr[k & 7], b, acc, 0, 0, 0);
  }
  if (chain) {
#pragma unroll
    for (int reg = 0; reg < 16; ++reg) redB[p][reg][lane] = acc[reg];
  }
  __syncthreads();
  if (!chain) {
    const int cb = p * 32 + r2;
    const float bias = brel[cb];
#pragma unroll
    for (int reg = 0; reg < 16; ++reg) {
      const int orow = r0 + (reg & 3) + 8 * (reg >> 2) + 4 * hseg;
      if (orow < N_NODES)
        outp[(size_t)orow * D + cb] =
            f2bf(fmaxf(acc[reg] + redB[p][reg][lane] + bias, 0.f));
    }
  }
}

// ============= pool (segment ranges; batch sorted) + MLP head ===============
__device__ __forceinline__ int lb_search(const int* __restrict__ a, int n, int key) {
  int lo = 0, hi = n;
  while (lo < hi) {
    int m = (lo + hi) >> 1;
    if (a[m] < key) lo = m + 1; else hi = m;
  }
  return lo;
}

__global__ __launch_bounds__(256) void pool_head_kernel(
    const unsigned short* __restrict__ h, const int* __restrict__ batch,
    const float* __restrict__ W1, const float* __restrict__ b1,
    const float* __restrict__ W2, const float* __restrict__ b2,
    float* __restrict__ out) {
  __shared__ float sums_lds[16][128];
  __shared__ float pooled[128];
  __shared__ float hidden[128];
  __shared__ int range[2];
  const int g = blockIdx.x;
  const int t = threadIdx.x;
  if (t < 2) range[t] = lb_search(batch, N_NODES, g + t);
  __syncthreads();
  const int lo = range[0], hi = range[1];
  const int rg = t >> 4, cg = t & 15;
  float a0 = 0, a1 = 0, a2 = 0, a3 = 0, a4 = 0, a5 = 0, a6 = 0, a7 = 0;
  for (int n = lo + rg; n < hi; n += 16) {
    const uint4 v = *(const uint4*)&h[(size_t)n * D + cg * 8];
    a0 += blo(v.x); a1 += bhi(v.x);
    a2 += blo(v.y); a3 += bhi(v.y);
    a4 += blo(v.z); a5 += bhi(v.z);
    a6 += blo(v.w); a7 += bhi(v.w);
  }
  sums_lds[rg][cg * 8 + 0] = a0; sums_lds[rg][cg * 8 + 1] = a1;
  sums_lds[rg][cg * 8 + 2] = a2; sums_lds[rg][cg * 8 + 3] = a3;
  sums_lds[rg][cg * 8 + 4] = a4; sums_lds[rg][cg * 8 + 5] = a5;
  sums_lds[rg][cg * 8 + 6] = a6; sums_lds[rg][cg * 8 + 7] = a7;
  __syncthreads();
  if (t < 128) {
    float s = 0.f;
#pragma unroll
    for (int r = 0; r < 16; ++r) s += sums_lds[r][t];
    pooled[t] = s / fmaxf((float)(hi - lo), 1.f);
  }
  __syncthreads();
  if (t < 128) {
    float a = b1[t];
    for (int k = 0; k < D; ++k) a += pooled[k] * W1[k * D + t];
    hidden[t] = a;
  }
  __syncthreads();
  if (t < OUT_F) {
    float o = b2[t];
    for (int k = 0; k < D; ++k) o += hidden[k] * W2[k * OUT_F + t];
    out[(size_t)g * OUT_F + t] = o;
  }
}

// ============================== launch ======================================
extern "C" void kernel_launch(void* const* d_in, const int* in_sizes, int n_in,
                              void* d_out, int out_size, void* d_ws, size_t ws_size,
                              hipStream_t stream) {
  const float* x     = (const float*)d_in[0];
  const int*   ei    = (const int*)d_in[1];
  const int*   batch = (const int*)d_in[2];
  const float* Wrel  = (const float*)d_in[3];
  const float* brel  = (const float*)d_in[4];
  const float* Wroot = (const float*)d_in[5];
  const float* W1    = (const float*)d_in[6];
  const float* b1    = (const float*)d_in[7];
  const float* W2    = (const float*)d_in[8];
  const float* b2    = (const float*)d_in[9];
  float* out = (float*)d_out;

  const size_t ND = (size_t)N_NODES * D;
  unsigned short* bufA = (unsigned short*)d_ws;            // N*D bf16
  unsigned short* bufB = bufA + ND;                        // N*D bf16
  unsigned short* bufC = bufB + ND;                        // N*D bf16 (x16)
  unsigned short* wt   = bufC + ND;                        // 3*128*512 bf16
  int* rowbeg = (int*)(wt + (size_t)N_LAYERS * 128 * 512); // N
  int* rowend = rowbeg + N_NODES;                          // N
  int* esrc   = rowend + N_NODES;                          // NBUCK*CAP
  unsigned* pairs = (unsigned*)(esrc + (size_t)NBUCK * CAP);  // NBUCK*CAP
  int* cursor = (int*)(pairs + (size_t)NBUCK * CAP);       // NBUCK

  const int* esrc_in = ei;
  const int* edst_in = ei + N_EDGES;

  // ---- prep (partition + cast + weight frags) then bucket sort ----
  hipMemsetAsync(cursor, 0, NBUCK * sizeof(int), stream);
  prep_part_kernel<<<NB3 + NCAST + NPREPW, 256, 0, stream>>>(
      esrc_in, edst_in, cursor, pairs, x, bufC, Wrel, Wroot, wt);
  bucket_sort_kernel<<<NBUCK, 256, 0, stream>>>(pairs, cursor, rowbeg, rowend, esrc);

  // ---- 3 fused layers (gather + GEMM in one kernel each) ----
  const size_t WL = (size_t)128 * 512;
  layer_kernel<<<NT32, 512, 0, stream>>>(bufC, rowbeg, rowend, esrc,
                                         wt, brel, bufA);
  layer_kernel<<<NT32, 512, 0, stream>>>(bufA, rowbeg, rowend, esrc,
                                         wt + WL, brel + D, bufB);
  layer_kernel<<<NT32, 512, 0, stream>>>(bufB, rowbeg, rowend, esrc,
                                         wt + 2 * WL, brel + 2 * D, bufA);

  pool_head_kernel<<<N_GRAPHS, 256, 0, stream>>>(bufA, batch, W1, b1, W2, b2, out);
}

// Round 13
// 245.479 us; speedup vs baseline: 1.1232x; 1.0639x over previous
//
#include <hip/hip_runtime.h>

#define N_NODES 50000
#define N_EDGES 800000
#define D 128
#define N_LAYERS 3
#define OUT_F 16
#define N_GRAPHS 128
#define NBUCK 391            // ceil(50000/128) buckets of 128 nodes
#define EPB 4096             // edges per partition block
#define NB3 ((N_EDGES + EPB - 1) / EPB)  // 196
#define CAP 4096             // padded bucket capacity (mean 2048, sigma ~45)
#define NT64 ((N_NODES + 63) / 64)       // 782 row-tiles of 64
#define PITCH 132            // LDS tile pitch in shorts (264B)
#define NCAST 6250           // cast blocks: 50000*128/4/256
#define NPREPW 96            // prep_w blocks: 24576/256

typedef __attribute__((ext_vector_type(8))) short short8;
typedef __attribute__((ext_vector_type(16))) float floatx16;

__device__ __forceinline__ unsigned short f2bf(float f) {
  unsigned int u = __float_as_uint(f);
  u += 0x7fff + ((u >> 16) & 1);   // RNE
  return (unsigned short)(u >> 16);
}
__device__ __forceinline__ float bf2f(unsigned short b) {
  return __uint_as_float(((unsigned int)b) << 16);
}
__device__ __forceinline__ float blo(unsigned v) { return __uint_as_float(v << 16); }
__device__ __forceinline__ float bhi(unsigned v) { return __uint_as_float(v & 0xffff0000u); }

// ====== prep_part: partition + cast x + weight frags in ONE dispatch ========
// (cursor zeroed by hipMemsetAsync before this dispatch)
__global__ __launch_bounds__(256) void prep_part_kernel(
    const int* __restrict__ src, const int* __restrict__ dst,
    int* __restrict__ cursor, unsigned* __restrict__ pairs,
    const float* __restrict__ x, unsigned short* __restrict__ x16,
    const float* __restrict__ Wrel, const float* __restrict__ Wroot,
    unsigned short* __restrict__ wt) {
  __shared__ unsigned pk[EPB];
  __shared__ int hist[NBUCK];
  __shared__ int wcur[NBUCK];
  const int bid = blockIdx.x;
  const int t = threadIdx.x;
  if (bid < NB3) {                         // ---- edge partition ----
    const int e0 = bid * EPB;
    const int n = min(EPB, N_EDGES - e0);
    for (int i = t; i < NBUCK; i += 256) hist[i] = 0;
    __syncthreads();
    for (int i = t; i < n; i += 256) {
      int d = dst[e0 + i], s = src[e0 + i];
      pk[i] = ((unsigned)d << 16) | (unsigned)s;
      atomicAdd(&hist[d >> 7], 1);
    }
    __syncthreads();
    for (int i = t; i < NBUCK; i += 256)
      wcur[i] = i * CAP + (hist[i] ? atomicAdd(&cursor[i], hist[i]) : 0);
    __syncthreads();
    for (int i = t; i < n; i += 256) {
      unsigned p = pk[i];
      int pos = atomicAdd(&wcur[p >> 23], 1);
      pairs[pos] = p;
    }
  } else if (bid < NB3 + NCAST) {          // ---- cast x (4 floats/thread) ----
    const int i = (bid - NB3) * 256 + t;
    const float4 v = *(const float4*)&x[(size_t)i * 4];
    uint2 o;
    o.x = f2bf(v.x) | ((unsigned)f2bf(v.y) << 16);
    o.y = f2bf(v.z) | ((unsigned)f2bf(v.w) << 16);
    *(uint2*)&x16[(size_t)i * 4] = o;
  } else {                                 // ---- weight fragments ----
    const int idx = (bid - NB3 - NCAST) * 256 + t;
    const int lane = idx & 63;
    const int kst = (idx >> 6) & 31;
    const int nt = (idx >> 11) & 1;
    const int half = (idx >> 12) & 1;
    const int l = idx >> 13;
    const int n = half * 64 + nt * 32 + (lane & 31);
    const int kx0 = kst * 16 + (lane >> 5) * 8;
    const int seg = kx0 >> 7;              // same seg for all 8 j
    const int k0 = kx0 & 127;
    const int mat = seg >> 1, lo = seg & 1;
    const float* W = (mat ? Wroot : Wrel) + (size_t)l * D * D;
    unsigned short v[8];
#pragma unroll
    for (int j = 0; j < 8; ++j) {
      float w = W[(size_t)(k0 + j) * D + n];
      unsigned short hi = f2bf(w);
      v[j] = lo ? f2bf(w - bf2f(hi)) : hi;
    }
    unsigned short* dstp =
        wt + ((size_t)l * 128 + (half * 2 + nt) * 32 + kst) * 512 + lane * 8;
    *(uint4*)dstp = *(const uint4*)v;
  }
}

__global__ __launch_bounds__(256) void bucket_sort_kernel(
    const unsigned* __restrict__ pairs, const int* __restrict__ cursor,
    int* __restrict__ rowbeg, int* __restrict__ rowend, int* __restrict__ esrc) {
  __shared__ unsigned pk[CAP];
  __shared__ int sorted[CAP];
  __shared__ int hist[128], off[128], cur[128];
  const int bkt = blockIdx.x;
  const int t = threadIdx.x;
  const int beg = bkt * CAP;
  const int cnt = cursor[bkt];
  if (t < 128) hist[t] = 0;
  __syncthreads();
  for (int i = t; i < cnt; i += 256) {
    unsigned p = pairs[beg + i];
    pk[i] = p;
    atomicAdd(&hist[(p >> 16) & 127], 1);
  }
  __syncthreads();
  if (t < 128) off[t] = hist[t];
  __syncthreads();
  for (int o = 1; o < 128; o <<= 1) {
    int x = (t < 128 && t >= o) ? off[t - o] : 0;
    __syncthreads();
    if (t < 128) off[t] += x;
    __syncthreads();
  }
  if (t < 128) {
    int node = bkt * 128 + t;
    if (node < N_NODES) {
      rowbeg[node] = beg + off[t] - hist[t];
      rowend[node] = beg + off[t];
    }
    cur[t] = off[t] - hist[t];
  }
  __syncthreads();
  for (int i = t; i < cnt; i += 256) {
    unsigned p = pk[i];
    int pos = atomicAdd(&cur[(p >> 16) & 127], 1);
    sorted[pos] = (int)(p & 0xFFFFu);
  }
  __syncthreads();
  for (int i = t; i < cnt; i += 256) esrc[beg + i] = sorted[i];
}

// ========== FUSED layer v13: 64-row block, ONE barrier, no redB =============
// 8-wave block = 2 tiles of 32 rows. Gather: 32 groups x 16 lanes, TWO rows
// per group (g and g+32), r4's proven inner loop, (512,8)/32-VGPR config
// (measured best). MFMA: wave w -> (tile w&1, phase w>>1); each wave runs
// BOTH chains (32 ksteps: rel 0-15 from atile, root 16-31 from htile) into
// one accumulator (r8's verified pattern) -> no redB exchange, no second
// barrier. One __syncthreads per block (was 2 + 16KB LDS round-trip).
__global__ __launch_bounds__(512, 8) void layer_kernel(
    const unsigned short* __restrict__ h,     // [N][128] bf16 row-major
    const int* __restrict__ rowbeg, const int* __restrict__ rowend,
    const int* __restrict__ esrc,
    const unsigned short* __restrict__ wt,    // this layer's 128KB frag block
    const float* __restrict__ brel,
    unsigned short* __restrict__ outp) {      // [N][128] bf16 row-major
  __shared__ unsigned short atile[64 * PITCH];  // agg tiles  (16.9 KB)
  __shared__ unsigned short htile[64 * PITCH];  // root tiles (16.9 KB)
  const int t = threadIdx.x;
  const int r0 = blockIdx.x * 64;
  const int g = t >> 4, li = t & 15;            // 32 groups x 16 lanes
  const unsigned short* hp = h + (size_t)li * 8;

#pragma unroll
  for (int rr = 0; rr < 2; ++rr) {
    const int lr = g + rr * 32;
    const int row = r0 + lr;
    // ---- stage root row (coalesced; zero tail rows) ----
    if (row < N_NODES) {
      *(uint4*)&htile[lr * PITCH + li * 8] =
          *(const uint4*)&h[(size_t)row * D + li * 8];
    } else {
      const uint4 z = {0, 0, 0, 0};
      *(uint4*)&htile[lr * PITCH + li * 8] = z;
    }
    // ---- gather: 16 lanes read full 256B source row, 4-edge unroll ----
    int beg = 0, end = 0;
    if (row < N_NODES) { beg = rowbeg[row]; end = rowend[row]; }
    float a0 = 0, a1 = 0, a2 = 0, a3 = 0, a4 = 0, a5 = 0, a6 = 0, a7 = 0;
    int e = beg;
    for (; e + 4 <= end; e += 4) {
      const int s0 = esrc[e],     s1 = esrc[e + 1];
      const int s2 = esrc[e + 2], s3 = esrc[e + 3];
      const uint4 v0 = *(const uint4*)&hp[(size_t)s0 * D];
      const uint4 v1 = *(const uint4*)&hp[(size_t)s1 * D];
      const uint4 v2 = *(const uint4*)&hp[(size_t)s2 * D];
      const uint4 v3 = *(const uint4*)&hp[(size_t)s3 * D];
      a0 += blo(v0.x) + blo(v1.x) + blo(v2.x) + blo(v3.x);
      a1 += bhi(v0.x) + bhi(v1.x) + bhi(v2.x) + bhi(v3.x);
      a2 += blo(v0.y) + blo(v1.y) + blo(v2.y) + blo(v3.y);
      a3 += bhi(v0.y) + bhi(v1.y) + bhi(v2.y) + bhi(v3.y);
      a4 += blo(v0.z) + blo(v1.z) + blo(v2.z) + blo(v3.z);
      a5 += bhi(v0.z) + bhi(v1.z) + bhi(v2.z) + bhi(v3.z);
      a6 += blo(v0.w) + blo(v1.w) + blo(v2.w) + blo(v3.w);
      a7 += bhi(v0.w) + bhi(v1.w) + bhi(v2.w) + bhi(v3.w);
    }
    for (; e < end; ++e) {
      const uint4 v0 = *(const uint4*)&hp[(size_t)esrc[e] * D];
      a0 += blo(v0.x); a1 += bhi(v0.x);
      a2 += blo(v0.y); a3 += bhi(v0.y);
      a4 += blo(v0.z); a5 += bhi(v0.z);
      a6 += blo(v0.w); a7 += bhi(v0.w);
    }
    uint4 o;
    o.x = f2bf(a0) | ((unsigned)f2bf(a1) << 16);
    o.y = f2bf(a2) | ((unsigned)f2bf(a3) << 16);
    o.z = f2bf(a4) | ((unsigned)f2bf(a5) << 16);
    o.w = f2bf(a6) | ((unsigned)f2bf(a7) << 16);
    *(uint4*)&atile[lr * PITCH + li * 8] = o;
  }
  __syncthreads();   // the only barrier

  // ---- MFMA: wave w = (tile w&1, phase w>>1); 32 ksteps, both chains ----
  const int wave = t >> 6, lane = t & 63;
  const int tl = wave & 1, p = wave >> 1;
  const int r2 = lane & 31, hseg = lane >> 5;
  const int rbase = tl * 32 + r2;
  short8 ag[8], hh[8];
#pragma unroll
  for (int i = 0; i < 8; ++i) {
    ag[i] = *(const short8*)&atile[rbase * PITCH + i * 16 + hseg * 8];
    hh[i] = *(const short8*)&htile[rbase * PITCH + i * 16 + hseg * 8];
  }
  const unsigned short* ws = wt + (size_t)p * 32 * 512;
  floatx16 acc = {0.f};
#pragma unroll
  for (int kst = 0; kst < 32; ++kst) {
    const short8 af = (kst < 16) ? ag[kst & 7] : hh[kst & 7];
    const short8 b = *(const short8*)&ws[(size_t)kst * 512 + lane * 8];
    acc = __builtin_amdgcn_mfma_f32_32x32x16_bf16(af, b, acc, 0, 0, 0);
  }
  const int cb = p * 32 + r2;
  const float bias = brel[cb];
#pragma unroll
  for (int reg = 0; reg < 16; ++reg) {
    const int orow = r0 + tl * 32 + (reg & 3) + 8 * (reg >> 2) + 4 * hseg;
    if (orow < N_NODES)
      outp[(size_t)orow * D + cb] = f2bf(fmaxf(acc[reg] + bias, 0.f));
  }
}

// ============= pool (segment ranges; batch sorted) + MLP head ===============
__device__ __forceinline__ int lb_search(const int* __restrict__ a, int n, int key) {
  int lo = 0, hi = n;
  while (lo < hi) {
    int m = (lo + hi) >> 1;
    if (a[m] < key) lo = m + 1; else hi = m;
  }
  return lo;
}

__global__ __launch_bounds__(256) void pool_head_kernel(
    const unsigned short* __restrict__ h, const int* __restrict__ batch,
    const float* __restrict__ W1, const float* __restrict__ b1,
    const float* __restrict__ W2, const float* __restrict__ b2,
    float* __restrict__ out) {
  __shared__ float sums_lds[16][128];
  __shared__ float pooled[128];
  __shared__ float hidden[128];
  __shared__ int range[2];
  const int g = blockIdx.x;
  const int t = threadIdx.x;
  if (t < 2) range[t] = lb_search(batch, N_NODES, g + t);
  __syncthreads();
  const int lo = range[0], hi = range[1];
  const int rg = t >> 4, cg = t & 15;
  float a0 = 0, a1 = 0, a2 = 0, a3 = 0, a4 = 0, a5 = 0, a6 = 0, a7 = 0;
  for (int n = lo + rg; n < hi; n += 16) {
    const uint4 v = *(const uint4*)&h[(size_t)n * D + cg * 8];
    a0 += blo(v.x); a1 += bhi(v.x);
    a2 += blo(v.y); a3 += bhi(v.y);
    a4 += blo(v.z); a5 += bhi(v.z);
    a6 += blo(v.w); a7 += bhi(v.w);
  }
  sums_lds[rg][cg * 8 + 0] = a0; sums_lds[rg][cg * 8 + 1] = a1;
  sums_lds[rg][cg * 8 + 2] = a2; sums_lds[rg][cg * 8 + 3] = a3;
  sums_lds[rg][cg * 8 + 4] = a4; sums_lds[rg][cg * 8 + 5] = a5;
  sums_lds[rg][cg * 8 + 6] = a6; sums_lds[rg][cg * 8 + 7] = a7;
  __syncthreads();
  if (t < 128) {
    float s = 0.f;
#pragma unroll
    for (int r = 0; r < 16; ++r) s += sums_lds[r][t];
    pooled[t] = s / fmaxf((float)(hi - lo), 1.f);
  }
  __syncthreads();
  if (t < 128) {
    float a = b1[t];
    for (int k = 0; k < D; ++k) a += pooled[k] * W1[k * D + t];
    hidden[t] = a;
  }
  __syncthreads();
  if (t < OUT_F) {
    float o = b2[t];
    for (int k = 0; k < D; ++k) o += hidden[k] * W2[k * OUT_F + t];
    out[(size_t)g * OUT_F + t] = o;
  }
}

// ============================== launch ======================================
extern "C" void kernel_launch(void* const* d_in, const int* in_sizes, int n_in,
                              void* d_out, int out_size, void* d_ws, size_t ws_size,
                              hipStream_t stream) {
  const float* x     = (const float*)d_in[0];
  const int*   ei    = (const int*)d_in[1];
  const int*   batch = (const int*)d_in[2];
  const float* Wrel  = (const float*)d_in[3];
  const float* brel  = (const float*)d_in[4];
  const float* Wroot = (const float*)d_in[5];
  const float* W1    = (const float*)d_in[6];
  const float* b1    = (const float*)d_in[7];
  const float* W2    = (const float*)d_in[8];
  const float* b2    = (const float*)d_in[9];
  float* out = (float*)d_out;

  const size_t ND = (size_t)N_NODES * D;
  unsigned short* bufA = (unsigned short*)d_ws;            // N*D bf16
  unsigned short* bufB = bufA + ND;                        // N*D bf16
  unsigned short* bufC = bufB + ND;                        // N*D bf16 (x16)
  unsigned short* wt   = bufC + ND;                        // 3*128*512 bf16
  int* rowbeg = (int*)(wt + (size_t)N_LAYERS * 128 * 512); // N
  int* rowend = rowbeg + N_NODES;                          // N
  int* esrc   = rowend + N_NODES;                          // NBUCK*CAP
  unsigned* pairs = (unsigned*)(esrc + (size_t)NBUCK * CAP);  // NBUCK*CAP
  int* cursor = (int*)(pairs + (size_t)NBUCK * CAP);       // NBUCK

  const int* esrc_in = ei;
  const int* edst_in = ei + N_EDGES;

  // ---- prep (partition + cast + weight frags) then bucket sort ----
  hipMemsetAsync(cursor, 0, NBUCK * sizeof(int), stream);
  prep_part_kernel<<<NB3 + NCAST + NPREPW, 256, 0, stream>>>(
      esrc_in, edst_in, cursor, pairs, x, bufC, Wrel, Wroot, wt);
  bucket_sort_kernel<<<NBUCK, 256, 0, stream>>>(pairs, cursor, rowbeg, rowend, esrc);

  // ---- 3 fused layers (gather + GEMM in one kernel each) ----
  const size_t WL = (size_t)128 * 512;
  layer_kernel<<<NT64, 512, 0, stream>>>(bufC, rowbeg, rowend, esrc,
                                         wt, brel, bufA);
  layer_kernel<<<NT64, 512, 0, stream>>>(bufA, rowbeg, rowend, esrc,
                                         wt + WL, brel + D, bufB);
  layer_kernel<<<NT64, 512, 0, stream>>>(bufB, rowbeg, rowend, esrc,
                                         wt + 2 * WL, brel + 2 * D, bufA);

  pool_head_kernel<<<N_GRAPHS, 256, 0, stream>>>(bufA, batch, W1, b1, W2, b2, out);
}